// Round 3
// baseline (70.823 us; speedup 1.0000x reference)
//
#include <hip/hip_runtime.h>

#define D_MODEL   256
#define NUM_TYPES 7
#define BATCH     2
#define NLANES    512

typedef __bf16 bf16x8 __attribute__((ext_vector_type(8)));
typedef float  floatx4 __attribute__((ext_vector_type(4)));

// ---------------- Kernel 1: H = [x@W1a + b1 | x@W1b] ----------------
// H is (1024 x 512) fp32 in ws. Cols 0..255 = hi+b1, 256..511 = hj.
// Block: 4 rows x 256 cols (one half of W1), thread = 1 row x 4 cols.
__global__ __launch_bounds__(256) void k_h_gemm(
    const float* __restrict__ x, const float* __restrict__ W1,
    const float* __restrict__ b1, float* __restrict__ H)
{
    __shared__ float xs[4][260];   // +4 pad: banks rg*4+k -> conflict-free broadcast
    const int tid  = threadIdx.x;
    const int half = blockIdx.x;   // 0 = hi (W1a, +b1), 1 = hj (W1b)
    const int r0   = blockIdx.y * 4;

    {   // stage 4 rows of x (1024 floats, 1 float4/thread)
        const float4 v = ((const float4*)(x + (size_t)r0 * D_MODEL))[tid];
        const int r  = tid >> 6;
        const int kq = (tid & 63) << 2;
        *(float4*)&xs[r][kq] = v;
    }
    __syncthreads();

    const int c  = (tid & 63) * 4;
    const int rg = tid >> 6;
    const float* Wb = W1 + (size_t)half * D_MODEL * D_MODEL + c;

    float a0 = 0.f, a1 = 0.f, a2 = 0.f, a3 = 0.f;
    #pragma unroll 8
    for (int k = 0; k < D_MODEL; ++k) {
        const float4 wv = *(const float4*)(Wb + (size_t)k * D_MODEL);
        const float  xv = xs[rg][k];
        a0 = fmaf(xv, wv.x, a0);
        a1 = fmaf(xv, wv.y, a1);
        a2 = fmaf(xv, wv.z, a2);
        a3 = fmaf(xv, wv.w, a3);
    }
    if (half == 0) {
        const float4 bv = *(const float4*)(b1 + c);
        a0 += bv.x; a1 += bv.y; a2 += bv.z; a3 += bv.w;
    }
    const float4 o = {a0, a1, a2, a3};
    *(float4*)(H + (size_t)(r0 + rg) * 512 + half * D_MODEL + c) = o;
}

// ---------------- Kernel 2 (MFMA): out[b,i,j,:] = relu(Hi[i]+Hj[j]) @ W2 + b2 ----
// Wave: 16-wide j-group, 8 i values. mfma_f32_16x16x32_bf16:
//   A[row][k]: row=lane&15 (type), k=(lane>>4)*8+e   (W2^T, resident in VGPRs)
//   B[k][col]: col=lane&15 (j),   k=(lane>>4)*8+e    (activation, built on the fly)
//   D[row][col]: col=lane&15 (j), row=(lane>>4)*4+r  (type)
// Hj tile in LDS with float4-granule XOR swizzle: slot q holds logical q^(jr&7).
// Since kc*8 occupies bits>=3 and (g2^sj) bits 0..2, swizzled read addr =
// loop-invariant base + kc*128B immediate -> zero per-iter address VALU.
__global__ __launch_bounds__(256, 4) void k_pair_mfma(
    const float* __restrict__ H, const float* __restrict__ W2,
    const float* __restrict__ b2, float* __restrict__ out)
{
    __shared__ __align__(16) float hjs[16 * 256];   // 16 KB, swizzled
    __shared__ __align__(16) float stg[4][112];     // per-wave 16j x 7t transpose tile

    const int tid  = threadIdx.x;
    const int lane = tid & 63;
    const int w    = tid >> 6;
    const int b    = blockIdx.z;
    const int j0   = blockIdx.x * 16;
    const int i0   = blockIdx.y * 32 + w * 8;

    // ---- stage Hj rows j0..j0+15 (cols 256..511 of H), swizzled store ----
    #pragma unroll
    for (int rr = 0; rr < 4; ++rr) {
        const int jrow = w * 4 + rr;
        const float* src = H + (size_t)(b * NLANES + j0 + jrow) * 512 + D_MODEL;
        const float4 v = *(const float4*)(src + lane * 4);
        *(float4*)&hjs[jrow * 256 + ((lane ^ (jrow & 7)) << 2)] = v;
    }

    // ---- A operand: W2^T fragments (32 VGPRs, resident) ----
    const int t  = lane & 15;
    const int g  = lane >> 4;         // 0..3
    const int ks = g * 8;
    bf16x8 w2f[8];
    #pragma unroll
    for (int kc = 0; kc < 8; ++kc) {
        #pragma unroll
        for (int e = 0; e < 8; ++e) {
            const float v = (t < NUM_TYPES)
                ? W2[(size_t)(kc * 32 + ks + e) * NUM_TYPES + t] : 0.f;
            w2f[kc][e] = (__bf16)v;
        }
    }

    const int tb = g * 4;             // lanes<32: 0 or 4 (type row base)
    float bias[4];
    #pragma unroll
    for (int r = 0; r < 4; ++r)
        bias[r] = (tb + r < NUM_TYPES) ? b2[tb + r] : 0.f;

    __syncthreads();

    // ---- loop-invariant swizzled LDS read bases ----
    const int jr = lane & 15;         // j column
    const int sj = jr & 7;
    const int g2 = g * 2;
    const float* p0 = hjs + jr * 256 + ((g2       ^ sj) << 2);
    const float* p1 = hjs + jr * 256 + (((g2 + 1) ^ sj) << 2);

    const float* Hi = H + ((size_t)b * NLANES + i0) * 512 + ks;
    float* const stw = &stg[w][0];

    for (int ii = 0; ii < 8; ++ii) {
        const float* hi = Hi + (size_t)ii * 512;
        floatx4 acc = {0.f, 0.f, 0.f, 0.f};
        float4 qa[4], qb[4];

        // ---- kc 0..3: batch loads, then compute ----
        #pragma unroll
        for (int kc = 0; kc < 4; ++kc) {
            qa[kc] = *(const float4*)(hi + kc * 32);
            qb[kc] = *(const float4*)(hi + kc * 32 + 4);
        }
        #pragma unroll
        for (int kc = 0; kc < 4; ++kc) {
            const float4 pa = *(const float4*)(p0 + kc * 32);
            const float4 pb = *(const float4*)(p1 + kc * 32);
            bf16x8 bf;
            #pragma unroll
            for (int e = 0; e < 4; ++e) {
                bf[e]     = (__bf16)fmaxf(((const float*)&qa[kc])[e] + ((const float*)&pa)[e], 0.f);
                bf[e + 4] = (__bf16)fmaxf(((const float*)&qb[kc])[e] + ((const float*)&pb)[e], 0.f);
            }
            acc = __builtin_amdgcn_mfma_f32_16x16x32_bf16(w2f[kc], bf, acc, 0, 0, 0);
        }
        // ---- kc 4..7 ----
        #pragma unroll
        for (int kc = 0; kc < 4; ++kc) {
            qa[kc] = *(const float4*)(hi + (kc + 4) * 32);
            qb[kc] = *(const float4*)(hi + (kc + 4) * 32 + 4);
        }
        #pragma unroll
        for (int kc = 0; kc < 4; ++kc) {
            const float4 pa = *(const float4*)(p0 + (kc + 4) * 32);
            const float4 pb = *(const float4*)(p1 + (kc + 4) * 32);
            bf16x8 bf;
            #pragma unroll
            for (int e = 0; e < 4; ++e) {
                bf[e]     = (__bf16)fmaxf(((const float*)&qa[kc])[e] + ((const float*)&pa)[e], 0.f);
                bf[e + 4] = (__bf16)fmaxf(((const float*)&qb[kc])[e] + ((const float*)&pb)[e], 0.f);
            }
            acc = __builtin_amdgcn_mfma_f32_16x16x32_bf16(w2f[kc + 4], bf, acc, 0, 0, 0);
        }

        // ---- epilogue: LDS transpose -> one dense dwordx4 store ----
        if (lane < 32) {
            float* sp = stw + jr * 7 + tb;
            sp[0] = acc[0] + bias[0];
            sp[1] = acc[1] + bias[1];
            sp[2] = acc[2] + bias[2];
            if (tb == 0) sp[3] = acc[3] + bias[3];
        }
        float4 sv = {0.f, 0.f, 0.f, 0.f};
        if (lane < 28) sv = *(const float4*)(stw + lane * 4);
        float* orow = out + ((size_t)(b * NLANES + i0 + ii) * NLANES + j0) * NUM_TYPES;
        if (lane < 28) *(float4*)(orow + lane * 4) = sv;
    }
}

extern "C" void kernel_launch(void* const* d_in, const int* in_sizes, int n_in,
                              void* d_out, int out_size, void* d_ws, size_t ws_size,
                              hipStream_t stream) {
    const float* x  = (const float*)d_in[0];   // (2,512,256)
    const float* W1 = (const float*)d_in[1];   // (512,256)
    const float* b1 = (const float*)d_in[2];   // (256)
    const float* W2 = (const float*)d_in[3];   // (256,7)
    const float* b2 = (const float*)d_in[4];   // (7)
    float* out = (float*)d_out;                // (2,512,512,7) fp32
    float* H   = (float*)d_ws;                 // 1024*512 floats = 2 MB

    k_h_gemm<<<dim3(2, 256), 256, 0, stream>>>(x, W1, b1, H);
    k_pair_mfma<<<dim3(NLANES / 16, NLANES / 32, BATCH), 256, 0, stream>>>(H, W2, b2, out);
}

// Round 4
// 35.486 us; speedup vs baseline: 1.9958x; 1.9958x over previous
//
#include <hip/hip_runtime.h>

#define D_MODEL   256
#define NUM_TYPES 7
#define BATCH     2
#define NLANES    512

typedef __bf16    bf16x8  __attribute__((ext_vector_type(8)));
typedef _Float16  f16x8   __attribute__((ext_vector_type(8)));
typedef _Float16  f16x4   __attribute__((ext_vector_type(4)));
typedef float     floatx4 __attribute__((ext_vector_type(4)));

// ws layout (bytes):
//   H      @ 0        : 1024*512 f32  = 2 MB   (cols 0..255 = hi+b1, 256..511 = hj)
//   xh     @ 2 MB     : 1024*256 f16  = 512 KB
//   w1frag @ 2.5 MB   : 32 nt * 8 kc * 64 lane * 8 f16 = 256 KB
//   w2frag @ 2.75 MB  : 8 kc * 64 lane * 8 bf16 = 8 KB
#define WS_XH  (2u * 1024u * 1024u)
#define WS_W1F (WS_XH + 512u * 1024u)
#define WS_W2F (WS_W1F + 256u * 1024u)

// ---------------- Kernel 0: prep (casts + MFMA operand fragments) ----------------
__global__ __launch_bounds__(256) void k_prep(
    const float* __restrict__ x, const float* __restrict__ W1,
    const float* __restrict__ W2, _Float16* __restrict__ xh,
    _Float16* __restrict__ w1f, __bf16* __restrict__ w2f)
{
    const int bx = blockIdx.x, tid = threadIdx.x;
    if (bx < 256) {
        // cast x (2,512,256) f32 -> f16, one float4 per thread
        const int idx = (bx * 256 + tid) * 4;
        const float4 v = *(const float4*)(x + idx);
        f16x4 o = { (_Float16)v.x, (_Float16)v.y, (_Float16)v.z, (_Float16)v.w };
        *(f16x4*)(xh + idx) = o;
    } else if (bx < 320) {
        // w1 B-fragments for k1: frag id = ((nt*8 + kc)*64 + lane)
        // B[k][col]: col = lane&15 (n within tile), k = (lane>>4)*8 + e (+32kc)
        const int id   = (bx - 256) * 256 + tid;   // 0..16383
        const int lane = id & 63;
        const int kc   = (id >> 6) & 7;
        const int nt   = id >> 9;                  // 0..31
        const int t16  = lane & 15;
        const int ks   = (lane >> 4) * 8;
        const int half = nt >> 4;
        const int c    = (nt & 15) * 16 + t16;
        const float* src = W1 + (size_t)(half * 256 + kc * 32 + ks) * 256 + c;
        f16x8 frag;
        #pragma unroll
        for (int e = 0; e < 8; ++e) frag[e] = (_Float16)src[(size_t)e * 256];
        *(f16x8*)(w1f + (size_t)id * 8) = frag;
    } else {
        // w2 A-fragments for k2 (bf16): slot = kc*64 + lane, 512 slots
        #pragma unroll
        for (int s0 = 0; s0 < 2; ++s0) {
            const int s    = tid + s0 * 256;
            const int lane = s & 63;
            const int kc   = s >> 6;
            const int t    = lane & 15;
            const int ks   = (lane >> 4) * 8;
            bf16x8 frag;
            #pragma unroll
            for (int e = 0; e < 8; ++e) {
                const int k = kc * 32 + ks + e;
                frag[e] = (t < NUM_TYPES) ? (__bf16)W2[(size_t)k * NUM_TYPES + t]
                                          : (__bf16)0.f;
            }
            *(bf16x8*)(w2f + (size_t)s * 8) = frag;
        }
    }
}

// ---------------- Kernel 1: H = x @ [W1a|W1b] via f16 MFMA, f32 accumulate ------
// Wave = one 16x16 output tile. A = xh rows (i), B = w1frag (n cols).
// D layout: col(lane&15) = n, row(4g+r) = i.
__global__ __launch_bounds__(256) void k1_mfma(
    const _Float16* __restrict__ xh, const _Float16* __restrict__ w1f,
    const float* __restrict__ b1, float* __restrict__ H)
{
    const int tid  = threadIdx.x, lane = tid & 63, w = tid >> 6;
    const int nt   = blockIdx.x;                  // 0..31
    const int m0   = (blockIdx.y * 4 + w) * 16;   // i-tile base
    const int jr   = lane & 15, g = lane >> 4;

    const f16x8*    bfp = (const f16x8*)w1f + (size_t)nt * 512 + lane;  // +kc*64
    const _Float16* ap  = xh + (size_t)(m0 + jr) * 256 + g * 8;         // +kc*32

    floatx4 acc = {0.f, 0.f, 0.f, 0.f};
    #pragma unroll
    for (int kc = 0; kc < 8; ++kc) {
        const f16x8 a = *(const f16x8*)(ap + kc * 32);
        const f16x8 b = bfp[kc * 64];
        acc = __builtin_amdgcn_mfma_f32_16x16x32_f16(a, b, acc, 0, 0, 0);
    }

    const int n = nt * 16 + jr;
    const float bias = (n < D_MODEL) ? b1[n] : 0.f;
    float* hp = H + (size_t)(m0 + g * 4) * 512 + n;
    #pragma unroll
    for (int r = 0; r < 4; ++r) hp[(size_t)r * 512] = acc[r] + bias;
}

// ---------------- Kernel 2: out[b,i,j,:] = relu(Hi[i]+Hj[j]) @ W2 + b2 ----------
// Wave: 16 j's x 8 i's (2 passes of 4-way i-blocking; each hj LDS read feeds 4 MFMAs).
// A = w2frag (types), B = activation built on the fly.
// D layout: col(lane&15) = j, row(4g+r) = type.
__global__ __launch_bounds__(256, 4) void k2_pair(
    const float* __restrict__ H, const __bf16* __restrict__ w2f,
    const float* __restrict__ b2, float* __restrict__ out)
{
    __shared__ float hjs[16][260];   // +4 pad: measured 0 bank conflicts (round 1)

    const int tid = threadIdx.x, lane = tid & 63, w = tid >> 6;
    const int b   = blockIdx.z;
    const int j0  = blockIdx.x * 16;
    const int i0  = blockIdx.y * 32 + w * 8;

    // stage Hj rows j0..j0+15 (cols 256..511 of H)
    #pragma unroll
    for (int q = 0; q < 4; ++q) {
        const int f  = tid + q * 256;
        const int r  = f >> 6;
        const int kk = (f & 63) << 2;
        const float4 v = *(const float4*)(
            H + (size_t)(b * NLANES + j0 + r) * 512 + D_MODEL + kk);
        *(float4*)&hjs[r][kk] = v;
    }

    // W2^T A-fragments: 8 coalesced 16B loads
    bf16x8 w2r[8];
    #pragma unroll
    for (int kc = 0; kc < 8; ++kc)
        w2r[kc] = ((const bf16x8*)w2f)[kc * 64 + lane];

    const int jr = lane & 15, g = lane >> 4;
    const int tb = g * 4;
    float bias[4];
    #pragma unroll
    for (int r = 0; r < 4; ++r)
        bias[r] = (tb + r < NUM_TYPES) ? b2[tb + r] : 0.f;

    __syncthreads();

    const float* hjp = &hjs[jr][g * 8];                       // + kc*32
    const float* Hi  = H + ((size_t)b * NLANES + i0) * 512 + g * 8;

    #pragma unroll
    for (int p = 0; p < 2; ++p) {
        const float* hi = Hi + (size_t)(p * 4) * 512;
        floatx4 acc[4];
        #pragma unroll
        for (int u = 0; u < 4; ++u) acc[u] = (floatx4){0.f, 0.f, 0.f, 0.f};

        #pragma unroll
        for (int kc = 0; kc < 8; ++kc) {
            const float4 ha = *(const float4*)(hjp + kc * 32);
            const float4 hb = *(const float4*)(hjp + kc * 32 + 4);
            #pragma unroll
            for (int u = 0; u < 4; ++u) {
                const float4 qa = *(const float4*)(hi + (size_t)u * 512 + kc * 32);
                const float4 qb = *(const float4*)(hi + (size_t)u * 512 + kc * 32 + 4);
                bf16x8 frag;
                frag[0] = (__bf16)fmaxf(qa.x + ha.x, 0.f);
                frag[1] = (__bf16)fmaxf(qa.y + ha.y, 0.f);
                frag[2] = (__bf16)fmaxf(qa.z + ha.z, 0.f);
                frag[3] = (__bf16)fmaxf(qa.w + ha.w, 0.f);
                frag[4] = (__bf16)fmaxf(qb.x + hb.x, 0.f);
                frag[5] = (__bf16)fmaxf(qb.y + hb.y, 0.f);
                frag[6] = (__bf16)fmaxf(qb.z + hb.z, 0.f);
                frag[7] = (__bf16)fmaxf(qb.w + hb.w, 0.f);
                acc[u] = __builtin_amdgcn_mfma_f32_16x16x32_bf16(w2r[kc], frag, acc[u], 0, 0, 0);
            }
        }

        // store: lane<32 holds D[tb..tb+3][jr]; round-1 pattern (fully merged writes)
        if (lane < 32) {
            #pragma unroll
            for (int u = 0; u < 4; ++u) {
                float* op = out + ((size_t)(b * NLANES + i0 + p * 4 + u) * NLANES
                                   + (j0 + jr)) * NUM_TYPES + tb;
                if (tb == 0) {
                    float v4[4] = { acc[u][0] + bias[0], acc[u][1] + bias[1],
                                    acc[u][2] + bias[2], acc[u][3] + bias[3] };
                    __builtin_memcpy(op, v4, 16);
                } else {
                    float v2[2] = { acc[u][0] + bias[0], acc[u][1] + bias[1] };
                    __builtin_memcpy(op, v2, 8);
                    op[2] = acc[u][2] + bias[2];
                }
            }
        }
    }
}

extern "C" void kernel_launch(void* const* d_in, const int* in_sizes, int n_in,
                              void* d_out, int out_size, void* d_ws, size_t ws_size,
                              hipStream_t stream) {
    const float* x  = (const float*)d_in[0];   // (2,512,256)
    const float* W1 = (const float*)d_in[1];   // (512,256)
    const float* b1 = (const float*)d_in[2];   // (256)
    const float* W2 = (const float*)d_in[3];   // (256,7)
    const float* b2 = (const float*)d_in[4];   // (7)
    float* out = (float*)d_out;                // (2,512,512,7) fp32

    char* ws = (char*)d_ws;
    float*     H   = (float*)ws;
    _Float16*  xh  = (_Float16*)(ws + WS_XH);
    _Float16*  w1f = (_Float16*)(ws + WS_W1F);
    __bf16*    w2f = (__bf16*)(ws + WS_W2F);

    k_prep<<<321, 256, 0, stream>>>(x, W1, W2, xh, w1f, w2f);
    k1_mfma<<<dim3(32, 16), 256, 0, stream>>>(xh, w1f, b1, H);
    k2_pair<<<dim3(NLANES / 16, NLANES / 32, BATCH), 256, 0, stream>>>(H, w2f, b2, out);
}

// Round 5
// 33.946 us; speedup vs baseline: 2.0864x; 1.0454x over previous
//
#include <hip/hip_runtime.h>

#define D_MODEL   256
#define NUM_TYPES 7
#define BATCH     2
#define NLANES    512

typedef _Float16  f16x8   __attribute__((ext_vector_type(8)));
typedef float     floatx4 __attribute__((ext_vector_type(4)));

// ws layout: Hi16 @ 0 (1024*256 f16 = 512 KB), Hj16 @ 512 KB (512 KB)
// Hi16[b*512+i][k] = (x@W1a + b1)[i][k] in f16 ; Hj16 = (x@W1b) in f16.

// ---------------- Kernel 1: H16 = f16(x @ [W1a|W1b] (+b1)) via f16 MFMA ----------
// Wave = one 16x16 output tile of one half. Operands built inline:
//   A[row][k]: row = lane&15 (= output row i), k = (lane>>4)*8+e (+32kc) — from x, cvt f32->f16
//   B[k][col]: col = lane&15 (= output col n), k = (lane>>4)*8+e (+32kc) — strided loads of W1
//   D[row][col]: col = lane&15 (n), row = (lane>>4)*4+r (i)
__global__ __launch_bounds__(256) void k1_mfma(
    const float* __restrict__ x, const float* __restrict__ W1,
    const float* __restrict__ b1, _Float16* __restrict__ Hi16,
    _Float16* __restrict__ Hj16)
{
    const int tid  = threadIdx.x, lane = tid & 63, w = tid >> 6;
    const int nt   = blockIdx.x;                  // 0..31 ; half = nt>>4
    const int half = nt >> 4;
    const int nc   = (nt & 15) * 16;              // n base within the half
    const int m0   = (blockIdx.y * 4 + w) * 16;   // row-tile base (0..1008)
    const int jr   = lane & 15, g = lane >> 4, ks = g * 8;

    const float* xrow = x + (size_t)(m0 + jr) * D_MODEL + ks;                 // +kc*32
    const float* wb   = W1 + (size_t)(half * D_MODEL + ks) * D_MODEL + nc + jr; // +kc*32*256, +e*256

    floatx4 acc = {0.f, 0.f, 0.f, 0.f};
    #pragma unroll
    for (int kc = 0; kc < 8; ++kc) {
        const float4 qa = *(const float4*)(xrow + kc * 32);
        const float4 qb = *(const float4*)(xrow + kc * 32 + 4);
        f16x8 a, bfr;
        a[0] = (_Float16)qa.x; a[1] = (_Float16)qa.y;
        a[2] = (_Float16)qa.z; a[3] = (_Float16)qa.w;
        a[4] = (_Float16)qb.x; a[5] = (_Float16)qb.y;
        a[6] = (_Float16)qb.z; a[7] = (_Float16)qb.w;
        const float* wp = wb + (size_t)(kc * 32) * D_MODEL;
        #pragma unroll
        for (int e = 0; e < 8; ++e)
            bfr[e] = (_Float16)wp[(size_t)e * D_MODEL];
        acc = __builtin_amdgcn_mfma_f32_16x16x32_f16(a, bfr, acc, 0, 0, 0);
    }

    _Float16* Hb = half ? Hj16 : Hi16;
    const float bias = half ? 0.f : b1[nc + jr];
    #pragma unroll
    for (int r = 0; r < 4; ++r)
        Hb[(size_t)(m0 + g * 4 + r) * D_MODEL + nc + jr] = (_Float16)(acc[r] + bias);
}

// ---------------- Kernel 2: out[b,i,j,:] = relu(Hi[i]+Hj[j]) @ W2 + b2 ----------
// Wave: 16 j's x 8 i's (2 passes x 4-way i-blocking). Activation built with
// packed f16 math: 4 v_pk_add_f16 + 4 v_pk_max_f16 per MFMA.
//   A = W2^T f16 frags (resident), B = activation, D: col=j (lane&15), row=type (4g+r).
__global__ __launch_bounds__(256, 4) void k2_pair(
    const _Float16* __restrict__ Hi16, const _Float16* __restrict__ Hj16,
    const float* __restrict__ W2, const float* __restrict__ b2,
    float* __restrict__ out)
{
    __shared__ _Float16 hjs[16][264];   // pad 264: b128 granule = 33jr+4kc+g -> 2-way (free)

    const int tid = threadIdx.x, lane = tid & 63, w = tid >> 6;
    const int b   = blockIdx.z;
    const int j0  = blockIdx.x * 16;
    const int i0  = blockIdx.y * 32 + w * 8;

    // ---- stage Hj16 rows j0..j0+15 (8 KB), 2 x 16B per thread, coalesced ----
    #pragma unroll
    for (int q = 0; q < 2; ++q) {
        const int f  = tid + q * 256;   // 0..511
        const int r  = f >> 5;          // row 0..15
        const int gg = f & 31;          // 16B granule in row
        const f16x8 v = *(const f16x8*)(
            Hj16 + (size_t)(b * NLANES + j0 + r) * D_MODEL + gg * 8);
        *(f16x8*)&hjs[r][gg * 8] = v;
    }

    // ---- A operand: W2^T f16 frags, built inline (L2-hot scalars) ----
    const int t  = lane & 15;
    const int g  = lane >> 4, ks = g * 8;
    f16x8 w2r[8];
    #pragma unroll
    for (int kc = 0; kc < 8; ++kc) {
        #pragma unroll
        for (int e = 0; e < 8; ++e) {
            const int k = kc * 32 + ks + e;
            w2r[kc][e] = (t < NUM_TYPES) ? (_Float16)W2[(size_t)k * NUM_TYPES + t]
                                         : (_Float16)0.f;
        }
    }

    const int jr = lane & 15;
    const int tb = g * 4;
    float bias[4];
    #pragma unroll
    for (int r = 0; r < 4; ++r)
        bias[r] = (tb + r < NUM_TYPES) ? b2[tb + r] : 0.f;

    __syncthreads();

    const _Float16* hjp = &hjs[jr][ks];                                   // +kc*32
    const _Float16* Hi  = Hi16 + (size_t)(b * NLANES + i0) * D_MODEL + ks; // +u*256+kc*32

    #pragma unroll
    for (int p = 0; p < 2; ++p) {
        const _Float16* hi = Hi + (size_t)(p * 4) * D_MODEL;
        floatx4 acc[4];
        #pragma unroll
        for (int u = 0; u < 4; ++u) acc[u] = (floatx4){0.f, 0.f, 0.f, 0.f};

        #pragma unroll
        for (int kc = 0; kc < 8; ++kc) {
            const f16x8 hj = *(const f16x8*)(hjp + kc * 32);   // ds_read_b128
            #pragma unroll
            for (int u = 0; u < 4; ++u) {
                const f16x8 hv = *(const f16x8*)(hi + (size_t)u * D_MODEL + kc * 32);
                f16x8 s = hv + hj;                             // 4x v_pk_add_f16
                const f16x8 z = {};
                s = __builtin_elementwise_max(s, z);           // 4x v_pk_max_f16
                acc[u] = __builtin_amdgcn_mfma_f32_16x16x32_f16(w2r[kc], s, acc[u], 0, 0, 0);
            }
        }

        // ---- store: lane<32 holds D[tb..tb+3][jr] (round-1 pattern, exact WRITE) ----
        if (lane < 32) {
            #pragma unroll
            for (int u = 0; u < 4; ++u) {
                float* op = out + ((size_t)(b * NLANES + i0 + p * 4 + u) * NLANES
                                   + (j0 + jr)) * NUM_TYPES + tb;
                if (tb == 0) {
                    float v4[4] = { acc[u][0] + bias[0], acc[u][1] + bias[1],
                                    acc[u][2] + bias[2], acc[u][3] + bias[3] };
                    __builtin_memcpy(op, v4, 16);
                } else {
                    float v2[2] = { acc[u][0] + bias[0], acc[u][1] + bias[1] };
                    __builtin_memcpy(op, v2, 8);
                    op[2] = acc[u][2] + bias[2];
                }
            }
        }
    }
}

extern "C" void kernel_launch(void* const* d_in, const int* in_sizes, int n_in,
                              void* d_out, int out_size, void* d_ws, size_t ws_size,
                              hipStream_t stream) {
    const float* x  = (const float*)d_in[0];   // (2,512,256)
    const float* W1 = (const float*)d_in[1];   // (512,256)
    const float* b1 = (const float*)d_in[2];   // (256)
    const float* W2 = (const float*)d_in[3];   // (256,7)
    const float* b2 = (const float*)d_in[4];   // (7)
    float* out = (float*)d_out;                // (2,512,512,7) fp32

    char* ws = (char*)d_ws;
    _Float16* Hi16 = (_Float16*)ws;
    _Float16* Hj16 = (_Float16*)(ws + 512u * 1024u);

    k1_mfma<<<dim3(32, 16), 256, 0, stream>>>(x, W1, b1, Hi16, Hj16);
    k2_pair<<<dim3(NLANES / 16, NLANES / 32, BATCH), 256, 0, stream>>>(
        Hi16, Hj16, W2, b2, out);
}